// Round 7
// baseline (474.667 us; speedup 1.0000x reference)
//
#include <hip/hip_runtime.h>

// TensorTrain: BS=16384, N_CH=8, H=256, RANK=16, N_AGGR=4, T=64, R=(16+1)*16=272
// Only r < 256 of ris is used (U_rank rows 0..15, b_rank = row 15 of tile 15).
//
// Round-9 = Round-8 with the double-counted "+1 at r=15" fixed:
//   the +1 is baked into the carry WRITE (init + publish) only; the fused
//   scan step is part += cv * (acc + bias)  -- no 'extra' term (r8 applied
//   both, weighting tile 15 by carry+2 -> absmax 12800).
// Register-diet schedule (fit under the backend's immovable 128-VGPR cap):
//   - B fragments read per-ks inside the MFMA loop (no Bq[8] batch)
//   - bias folded AFTER the MFMA chain: part += cv*(acc+bias), acc starts 0
//   - A-prefetch one self-contained phase (t=4 half0, t=10 half1):
//     f32 loads -> issueB -> pack -> ds_write (regs transient; the pack's
//     vmcnt wait leaves the newer B-DMA in flight)
// Unchanged: 512 thr = 8 waves = 4 aggr x 2 sample-waves (32 samples/wave ->
// B LDS reads halved), B double-buffered via global_load_lds, carry + bias
// double-buffered in LDS, carry scan via broadcast ds_read, static 136 KB LDS.

#define N_CH   8
#define H_DIM  256
#define R_FULL 272

typedef __bf16 bf16x8 __attribute__((ext_vector_type(8)));
typedef float  f32x4  __attribute__((ext_vector_type(4)));

union BF8 {
  bf16x8 v;
  unsigned short s[8];
  uint4 q;
};

typedef __attribute__((address_space(3))) unsigned int       lds_u32;
typedef __attribute__((address_space(1))) const unsigned int glb_u32;

static __device__ __forceinline__ unsigned short f2bf(float x) {
  union { float f; unsigned int u; } t; t.f = x;
  unsigned int u = t.u;
  return (unsigned short)((u + 0x7FFFu + ((u >> 16) & 1u)) >> 16); // RNE
}
static __device__ __forceinline__ unsigned int pk2(float a, float b) {
  return (unsigned int)f2bf(a) | ((unsigned int)f2bf(b) << 16);
}
static __device__ __forceinline__ void ll16(const void* g, void* l) {
  __builtin_amdgcn_global_load_lds((glb_u32*)g, (lds_u32*)l, 16, 0, 0);
}

// ---- prep: U[c][a][h][r<256] f32 -> bf16 in MFMA B-fragment order:
// Ubf[ca][t][ks][lane][j]  (j=0..7 bf16, 16B per lane-frag), where
//   r = t*16 + (lane&15), h = ks*32 + (lane>>4)*8 + j.
__global__ void prep_U_kernel(const float* __restrict__ U, unsigned int* __restrict__ Ubf) {
  unsigned int idx  = blockIdx.x * 256u + threadIdx.x;   // 1,048,576 total
  unsigned int jp   = idx & 3u;
  unsigned int lane = (idx >> 2) & 63u;
  unsigned int ks   = (idx >> 8) & 7u;
  unsigned int t    = (idx >> 11) & 15u;
  unsigned int ca   = idx >> 15;
  unsigned int h = ks * 32u + (lane >> 4) * 8u + jp * 2u;
  unsigned int r = t * 16u + (lane & 15u);
  const float* src = U + ((size_t)ca * 256u + h) * R_FULL + r;
  Ubf[idx] = pk2(src[0], src[R_FULL]);   // h, h+1
}

// LDS layout (static, 136 KB):
//   B bufs:  2 x 32 KB ([aggr][ks][lane]16B)     at 0 / 32K
//   A buf:   32 KB ([sg][ks][lane]16B)           at 64K
//   carry:   2 x 16 KB ([a][sg][r][sq] f32x4)    at 96K / 112K
//   bias:    2 x 4 KB  ([a][r<256] f32)          at 128K / 132K
#define SM_B0      0
#define SM_B1      32768
#define SM_AB      65536
#define SM_C(q)    (98304 + (q) * 16384)
#define SM_BIAS(q) (131072 + (q) * 4096)
#define SM_TOTAL   139264

__global__ __launch_bounds__(512, 2)
void tt_main(const float* __restrict__ nh,            // (BS, 8, 256)
             const float* __restrict__ ty,            // (BS, 64)
             const char*  __restrict__ Ubf,           // frag-ordered bf16 U (4 MB)
             const float* __restrict__ bB,            // (8, 4, 1, 272)
             const float* __restrict__ Ut,            // (4, 64, 16)
             const float* __restrict__ bt,            // (4, 1, 16)
             const float* __restrict__ Uo,            // (4, 16, 256)
             const float* __restrict__ bo,            // (4, 1, 256)
             float* __restrict__ out)                 // (BS, 1024)
{
  __shared__ __align__(16) char smem[SM_TOTAL];
  const int tid  = threadIdx.x;
  const int lane = tid & 63;
  const int w    = tid >> 6;        // 0..7
  const int a    = w & 3;           // aggregator
  const int sw   = w >> 2;          // sample-wave (0/1): samples sw*32..sw*32+31
  const int b0   = blockIdx.x * 64; // block sample base
  const int row0 = b0 + sw * 32;
  const int lr   = lane & 15;
  const int lg   = lane >> 4;
  const int sq16 = lg * 16;         // sample-quad byte offset in carry rows

  // B-tile async loader: stage tile g into buf (g&1); wave w copies 4 chunks.
  auto issueB = [&](int g) {
    const int cB  = g >> 4;
    const int tB  = g & 15;
    const int bo_ = (g & 1) ? SM_B1 : SM_B0;
#pragma unroll
    for (int q = 0; q < 4; ++q) {
      const int ch = w * 4 + q;                       // 0..31
      const char* gp = Ubf + (((((size_t)cB * 4 + (ch >> 3)) * 16 + tB) * 8 + (ch & 7)) << 10)
                           + lane * 16;
      ll16(gp, smem + bo_ + ch * 1024);
    }
  };

  // ---- prologue: B(0) in flight; stage A(0), bias(0), init carry.
  issueB(0);

#pragma unroll
  for (int half = 0; half < 2; ++half) {           // A(0): 512 thr x 2 halves
    const int ht  = half * 512 + tid;
    const int sgs = ht >> 8, ksh = (ht >> 6) & 3, ln = ht & 63;
    const int row = sgs * 16 + (ln & 15);
#pragma unroll
    for (int p = 0; p < 2; ++p) {
      const int ks = ksh * 2 + p, k0 = ks * 32 + (ln >> 4) * 8;
      const float* s = nh + ((size_t)(b0 + row) * N_CH + 0) * H_DIM + k0;
      float4 x0 = *(const float4*)s, x1 = *(const float4*)(s + 4);
      uint4 qv;
      qv.x = pk2(x0.x, x0.y); qv.y = pk2(x0.z, x0.w);
      qv.z = pk2(x1.x, x1.y); qv.w = pk2(x1.z, x1.w);
      *(uint4*)(smem + SM_AB + ((sgs * 8 + ks) * 64 + ln) * 16) = qv;
    }
  }
  {                                                 // bias(0)
    const int idx2 = tid * 2, a_s = idx2 >> 8, r_s = idx2 & 255;
    const float* bp = bB + (size_t)a_s * R_FULL + r_s;
    float2 bv = { bp[0], bp[1] };
    *(float2*)(smem + SM_BIAS(0) + idx2 * 4) = bv;
  }
  // init carry: rank_ris0 = ty @ U_type[a] + b_type[a] (per sg), +1 at r==15
#pragma unroll
  for (int h = 0; h < 2; ++h) {
    const int rowb = row0 + h * 16;
    float btv = bt[a * 16 + lr];
    f32x4 acc = { btv, btv, btv, btv };
#pragma unroll
    for (int ks = 0; ks < 2; ++ks) {
      BF8 utf, af;
#pragma unroll
      for (int j = 0; j < 8; ++j) {
        utf.s[j] = f2bf(Ut[a * 1024 + (ks * 32 + lg * 8 + j) * 16 + lr]);
        af.s[j]  = f2bf(ty[(size_t)(rowb + lr) * 64 + ks * 32 + lg * 8 + j]);
      }
      acc = __builtin_amdgcn_mfma_f32_16x16x32_bf16(af.v, utf.v, acc, 0, 0, 0);
    }
    if (lr == 15) { acc[0] += 1.f; acc[1] += 1.f; acc[2] += 1.f; acc[3] += 1.f; }
    *(f32x4*)(smem + SM_C(0) + ((a * 4 + sw * 2 + h) * 16 + lr) * 64 + sq16) = acc;
  }

  BF8   Af[2][8];
  f32x4 part0, part1;

  // ---- channel scan
#pragma unroll 1
  for (int c = 0; c < N_CH; ++c) {
    const int cb = c & 1;
#pragma unroll
    for (int t = 0; t < 16; ++t) {
      const int g = c * 16 + t;
      __syncthreads();                 // tile-g DMA done; prev-buf reads done

      if ((t == 4 || t == 10) && c < 7) {
        // A(c+1) prefetch: one self-contained phase (half0 @t=4, half1 @t=10).
        // f32 loads issued BEFORE issueB so the pack waits vmcnt(4) and the
        // next B-DMA stays in flight.
        const int ht  = (t == 10 ? 512 : 0) + tid;
        const int sgs = ht >> 8, ksh = (ht >> 6) & 3, ln = ht & 63;
        const int row = sgs * 16 + (ln & 15);
        float4 x[2][2];
#pragma unroll
        for (int p = 0; p < 2; ++p) {
          const int ks = ksh * 2 + p, k0 = ks * 32 + (ln >> 4) * 8;
          const float* s = nh + ((size_t)(b0 + row) * N_CH + (c + 1)) * H_DIM + k0;
          x[p][0] = *(const float4*)s;
          x[p][1] = *(const float4*)(s + 4);
        }
        issueB(g + 1);
#pragma unroll
        for (int p = 0; p < 2; ++p) {
          const int ks = ksh * 2 + p;
          uint4 qv;
          qv.x = pk2(x[p][0].x, x[p][0].y); qv.y = pk2(x[p][0].z, x[p][0].w);
          qv.z = pk2(x[p][1].x, x[p][1].y); qv.w = pk2(x[p][1].z, x[p][1].w);
          *(uint4*)(smem + SM_AB + ((sgs * 8 + ks) * 64 + ln) * 16) = qv;
        }
      } else if (t == 7 && c < 7) {
        // bias(c+1): load + write in one phase (cb^1 buffer is idle this ch.)
        const int idx2 = tid * 2, a_s = idx2 >> 8, r_s = idx2 & 255;
        const float* bp = bB + ((size_t)(c + 1) * 4 + a_s) * R_FULL + r_s;
        float2 bv = { bp[0], bp[1] };
        issueB(g + 1);
        *(float2*)(smem + SM_BIAS(cb ^ 1) + idx2 * 4) = bv;
      } else {
        if (g + 1 < N_CH * 16) issueB(g + 1);
      }

      if (t == 0) {
        // A fragments for this wave's 2 sample-groups (reused for 16 tiles)
#pragma unroll
        for (int s2 = 0; s2 < 2; ++s2)
#pragma unroll
          for (int ks = 0; ks < 8; ++ks)
            Af[s2][ks].q = *(const uint4*)(smem + SM_AB +
                             (((sw * 2 + s2) * 8 + ks) * 64 + lane) * 16);
        part0[0] = part0[1] = part0[2] = part0[3] = 0.f;
        part1[0] = part1[1] = part1[2] = part1[3] = 0.f;
      }

      // ---- compute tile t: acc = A(64x256) x B(256x16); bias folded later.
      const int Bb = (t & 1) ? SM_B1 : SM_B0;
      f32x4 acc0, acc1;
      __builtin_amdgcn_s_setprio(1);
      {
        BF8 bf;
        bf.q = *(const uint4*)(smem + Bb + (a * 8 + 0) * 1024 + lane * 16);
        const f32x4 z = { 0.f, 0.f, 0.f, 0.f };
        acc0 = __builtin_amdgcn_mfma_f32_16x16x32_bf16(Af[0][0].v, bf.v, z, 0, 0, 0);
        acc1 = __builtin_amdgcn_mfma_f32_16x16x32_bf16(Af[1][0].v, bf.v, z, 0, 0, 0);
      }
#pragma unroll
      for (int ks = 1; ks < 8; ++ks) {
        BF8 bf;
        bf.q = *(const uint4*)(smem + Bb + (a * 8 + ks) * 1024 + lane * 16);
        acc0 = __builtin_amdgcn_mfma_f32_16x16x32_bf16(Af[0][ks].v, bf.v, acc0, 0, 0, 0);
        acc1 = __builtin_amdgcn_mfma_f32_16x16x32_bf16(Af[1][ks].v, bf.v, acc1, 0, 0, 0);
      }
      __builtin_amdgcn_s_setprio(0);

      // fused scan step: part += carry[r=t] * (acc + bias)
      // (+1 at r=15 is baked into the carry write -- no extra term here)
      const float bias = *(const float*)(smem + SM_BIAS(cb) + (a * 256 + t * 16 + lr) * 4);
      const f32x4 cv0  = *(const f32x4*)(smem + SM_C(cb) +
                           ((a * 4 + sw * 2    ) * 16 + t) * 64 + sq16);
      const f32x4 cv1  = *(const f32x4*)(smem + SM_C(cb) +
                           ((a * 4 + sw * 2 + 1) * 16 + t) * 64 + sq16);
#pragma unroll
      for (int i = 0; i < 4; ++i) {
        part0[i] += cv0[i] * (acc0[i] + bias);
        part1[i] += cv1[i] * (acc1[i] + bias);
      }
    }

    // ---- publish new carry into the other buffer (+1.0 baked at r==15)
    if (c < 7) {
      f32x4 p0 = part0, p1 = part1;
      if (lr == 15) {
        p0[0] += 1.f; p0[1] += 1.f; p0[2] += 1.f; p0[3] += 1.f;
        p1[0] += 1.f; p1[1] += 1.f; p1[2] += 1.f; p1[3] += 1.f;
      }
      *(f32x4*)(smem + SM_C(cb ^ 1) + ((a * 4 + sw * 2    ) * 16 + lr) * 64 + sq16) = p0;
      *(f32x4*)(smem + SM_C(cb ^ 1) + ((a * 4 + sw * 2 + 1) * 16 + lr) * 64 + sq16) = p1;
    }
  }

  // ---- epilogue: out[b][a*256+h] = carry[b][a][:] @ Uo[a][:][h] + bo[a][h]
  float uo[4][16], bov[4];
#pragma unroll
  for (int chk = 0; chk < 4; ++chk) {
    bov[chk] = bo[a * 256 + chk * 64 + lane];
#pragma unroll
    for (int r = 0; r < 16; ++r)
      uo[chk][r] = Uo[(size_t)a * 4096 + r * 256 + chk * 64 + lane];
  }
#pragma unroll
  for (int h = 0; h < 2; ++h) {
    const f32x4 cr   = h ? part1 : part0;
    const int   rowb = row0 + h * 16;
#pragma unroll
    for (int gq = 0; gq < 4; ++gq)
#pragma unroll
      for (int i = 0; i < 4; ++i) {
        const int m = gq * 4 + i;
        float cvv[16];
#pragma unroll
        for (int r = 0; r < 16; ++r) cvv[r] = __shfl(cr[i], (gq << 4) | r, 64);
#pragma unroll
        for (int chk = 0; chk < 4; ++chk) {
          float v = bov[chk];
#pragma unroll
          for (int r = 0; r < 16; ++r) v += cvv[r] * uo[chk][r];
          out[(size_t)(rowb + m) * 1024 + a * 256 + chk * 64 + lane] = v;
        }
      }
  }
}

extern "C" void kernel_launch(void* const* d_in, const int* in_sizes, int n_in,
                              void* d_out, int out_size, void* d_ws, size_t ws_size,
                              hipStream_t stream) {
  const float* nh = (const float*)d_in[0];   // neighbour_h (16384, 8, 256)
  const float* ty = (const float*)d_in[1];   // type_embs   (16384, 64)
  const float* U  = (const float*)d_in[2];   // U           (8, 4, 256, 272)
  const float* bB = (const float*)d_in[3];   // b           (8, 4, 1, 272)
  const float* Ut = (const float*)d_in[4];   // U_type      (4, 64, 16)
  const float* bt = (const float*)d_in[5];   // b_type      (4, 1, 16)
  const float* Uo = (const float*)d_in[6];   // U_output    (4, 16, 256)
  const float* bo = (const float*)d_in[7];   // b_output    (4, 1, 256)
  float* out = (float*)d_out;

  unsigned int* Ubf32 = (unsigned int*)d_ws; // 4 MB frag-ordered bf16 U

  prep_U_kernel<<<4096, 256, 0, stream>>>(U, Ubf32);

  tt_main<<<256, 512, 0, stream>>>(nh, ty, (const char*)d_ws,
                                   bB, Ut, bt, Uo, bo, out);
}

// Round 9
// 370.379 us; speedup vs baseline: 1.2816x; 1.2816x over previous
//
#include <hip/hip_runtime.h>

// TensorTrain: BS=16384, N_CH=8, H=256, RANK=16, N_AGGR=4, T=64, R=(16+1)*16=272
// Only r < 256 of ris is used (U_rank rows 0..15, b_rank = row 15 of tile 15).
//
// Round-10 (resubmitted; round-8 bench was an infra failure, kernel never ran):
// fit UNDER the immovable 128-VGPR cap instead of fighting it.
// r5/r6/r7/r9 (4 aggr x 2 sample-waves, Af[2][8]=64 regs, unrolled t-loop)
// all spilled ~400 MB/dispatch at VGPR_Count=128. This round re-partitions:
//   8 waves = 2 aggregator-PAIRS x 4 sample-waves. Each wave owns ONE
//   sample-group (Af[8] = 32 regs) and computes TWO aggregators (two acc
//   chains share the same A fragments). Live set ~90 < 128.
//   t-loop is '#pragma unroll 1' (runtime t) so the scheduler cannot hoist
//   across tiles and inflate peak pressure (r2 proved this shape stays lean).
// Price: B tiles are read by 4 waves instead of 2 (128 KB/CU/tile LDS) --
// cheap vs the ~390 MB/dispatch scratch round-trip it eliminates.
// Unchanged: B double-buffered via global_load_lds, A(c+1)/bias(c+1) staged
// mid-channel (A only read at t==0 so overwrite is safe), carry + bias
// double-buffered in LDS, carry scan via broadcast ds_read, "+1 at r=15"
// baked into carry writes only (r9 semantics, passed), static 136 KB LDS.

#define N_CH   8
#define H_DIM  256
#define R_FULL 272

typedef __bf16 bf16x8 __attribute__((ext_vector_type(8)));
typedef float  f32x4  __attribute__((ext_vector_type(4)));

union BF8 {
  bf16x8 v;
  unsigned short s[8];
  uint4 q;
};

typedef __attribute__((address_space(3))) unsigned int       lds_u32;
typedef __attribute__((address_space(1))) const unsigned int glb_u32;

static __device__ __forceinline__ unsigned short f2bf(float x) {
  union { float f; unsigned int u; } t; t.f = x;
  unsigned int u = t.u;
  return (unsigned short)((u + 0x7FFFu + ((u >> 16) & 1u)) >> 16); // RNE
}
static __device__ __forceinline__ unsigned int pk2(float a, float b) {
  return (unsigned int)f2bf(a) | ((unsigned int)f2bf(b) << 16);
}
static __device__ __forceinline__ void ll16(const void* g, void* l) {
  __builtin_amdgcn_global_load_lds((glb_u32*)g, (lds_u32*)l, 16, 0, 0);
}

// ---- prep: U[c][a][h][r<256] f32 -> bf16 in MFMA B-fragment order:
// Ubf[ca][t][ks][lane][j]  (j=0..7 bf16, 16B per lane-frag), where
//   r = t*16 + (lane&15), h = ks*32 + (lane>>4)*8 + j.
__global__ void prep_U_kernel(const float* __restrict__ U, unsigned int* __restrict__ Ubf) {
  unsigned int idx  = blockIdx.x * 256u + threadIdx.x;   // 1,048,576 total
  unsigned int jp   = idx & 3u;
  unsigned int lane = (idx >> 2) & 63u;
  unsigned int ks   = (idx >> 8) & 7u;
  unsigned int t    = (idx >> 11) & 15u;
  unsigned int ca   = idx >> 15;
  unsigned int h = ks * 32u + (lane >> 4) * 8u + jp * 2u;
  unsigned int r = t * 16u + (lane & 15u);
  const float* src = U + ((size_t)ca * 256u + h) * R_FULL + r;
  Ubf[idx] = pk2(src[0], src[R_FULL]);   // h, h+1
}

// LDS layout (static, 136 KB):
//   B bufs:  2 x 32 KB ([aggr][ks][lane]16B)     at 0 / 32K
//   A buf:   32 KB ([sg][ks][lane]16B)           at 64K
//   carry:   2 x 16 KB ([a][sg][r][sq] f32x4)    at 96K / 112K
//   bias:    2 x 4 KB  ([a][r<256] f32)          at 128K / 132K
#define SM_B0      0
#define SM_B1      32768
#define SM_AB      65536
#define SM_C(q)    (98304 + (q) * 16384)
#define SM_BIAS(q) (131072 + (q) * 4096)
#define SM_TOTAL   139264

__global__ __launch_bounds__(512, 2)
void tt_main(const float* __restrict__ nh,            // (BS, 8, 256)
             const float* __restrict__ ty,            // (BS, 64)
             const char*  __restrict__ Ubf,           // frag-ordered bf16 U (4 MB)
             const float* __restrict__ bB,            // (8, 4, 1, 272)
             const float* __restrict__ Ut,            // (4, 64, 16)
             const float* __restrict__ bt,            // (4, 1, 16)
             const float* __restrict__ Uo,            // (4, 16, 256)
             const float* __restrict__ bo,            // (4, 1, 256)
             float* __restrict__ out)                 // (BS, 1024)
{
  __shared__ __align__(16) char smem[SM_TOTAL];
  const int tid  = threadIdx.x;
  const int lane = tid & 63;
  const int w    = tid >> 6;        // 0..7
  const int ap   = w & 1;           // aggregator pair: aggrs {2ap, 2ap+1}
  const int sw   = w >> 1;          // sample-group 0..3 (16 samples each)
  const int a0   = ap * 2;
  const int a1   = ap * 2 + 1;
  const int b0   = blockIdx.x * 64; // block sample base
  const int rowb = b0 + sw * 16;    // wave sample base
  const int lr   = lane & 15;
  const int lg   = lane >> 4;
  const int sq16 = lg * 16;         // sample-quad byte offset in carry rows

  // B-tile async loader: stage tile g into buf (g&1); wave w copies 4 chunks.
  auto issueB = [&](int g) {
    const int cB  = g >> 4;
    const int tB  = g & 15;
    const int bo_ = (g & 1) ? SM_B1 : SM_B0;
#pragma unroll
    for (int q = 0; q < 4; ++q) {
      const int ch = w * 4 + q;                       // 0..31
      const char* gp = Ubf + (((((size_t)cB * 4 + (ch >> 3)) * 16 + tB) * 8 + (ch & 7)) << 10)
                           + lane * 16;
      ll16(gp, smem + bo_ + ch * 1024);
    }
  };

  // ---- prologue: B(0) in flight; stage A(0), bias(0), init carry.
  issueB(0);

#pragma unroll
  for (int half = 0; half < 2; ++half) {           // A(0): 512 thr x 2 halves
    const int ht  = half * 512 + tid;
    const int sgs = ht >> 8, ksh = (ht >> 6) & 3, ln = ht & 63;
    const int row = sgs * 16 + (ln & 15);
#pragma unroll
    for (int p = 0; p < 2; ++p) {
      const int ks = ksh * 2 + p, k0 = ks * 32 + (ln >> 4) * 8;
      const float* s = nh + ((size_t)(b0 + row) * N_CH + 0) * H_DIM + k0;
      float4 x0 = *(const float4*)s, x1 = *(const float4*)(s + 4);
      uint4 qv;
      qv.x = pk2(x0.x, x0.y); qv.y = pk2(x0.z, x0.w);
      qv.z = pk2(x1.x, x1.y); qv.w = pk2(x1.z, x1.w);
      *(uint4*)(smem + SM_AB + ((sgs * 8 + ks) * 64 + ln) * 16) = qv;
    }
  }
  {                                                 // bias(0)
    const int idx2 = tid * 2, a_s = idx2 >> 8, r_s = idx2 & 255;
    const float* bp = bB + (size_t)a_s * R_FULL + r_s;
    float2 bv = { bp[0], bp[1] };
    *(float2*)(smem + SM_BIAS(0) + idx2 * 4) = bv;
  }
  // init carry: rank_ris0 = ty @ U_type[a] + b_type[a], +1 baked at r==15.
  {
    BF8 af[2];
#pragma unroll
    for (int ks = 0; ks < 2; ++ks)
#pragma unroll
      for (int j = 0; j < 8; ++j)
        af[ks].s[j] = f2bf(ty[(size_t)(rowb + lr) * 64 + ks * 32 + lg * 8 + j]);
#pragma unroll
    for (int j = 0; j < 2; ++j) {
      const int aj = ap * 2 + j;
      float btv = bt[aj * 16 + lr];
      f32x4 acc = { btv, btv, btv, btv };
#pragma unroll
      for (int ks = 0; ks < 2; ++ks) {
        BF8 utf;
#pragma unroll
        for (int j2 = 0; j2 < 8; ++j2)
          utf.s[j2] = f2bf(Ut[aj * 1024 + (ks * 32 + lg * 8 + j2) * 16 + lr]);
        acc = __builtin_amdgcn_mfma_f32_16x16x32_bf16(af[ks].v, utf.v, acc, 0, 0, 0);
      }
      if (lr == 15) { acc[0] += 1.f; acc[1] += 1.f; acc[2] += 1.f; acc[3] += 1.f; }
      *(f32x4*)(smem + SM_C(0) + ((aj * 4 + sw) * 16 + lr) * 64 + sq16) = acc;
    }
  }

  BF8   Af[8];
  f32x4 part0, part1;

  // ---- channel scan
#pragma unroll 1
  for (int c = 0; c < N_CH; ++c) {
    const int cb = c & 1;
#pragma unroll 1
    for (int t = 0; t < 16; ++t) {
      const int g = c * 16 + t;
      __syncthreads();                 // tile-g DMA done; prev-buf reads done

      if (c < 7 && (t == 4 || t == 10)) {
        // A(c+1) prefetch: self-contained phase (half0 @t=4, half1 @t=10).
        // f32 loads issued BEFORE issueB so the pack's vmcnt wait leaves the
        // newer B-DMA in flight. SM_AB only read at t==0 -> overwrite safe.
        const int ht  = (t == 10 ? 512 : 0) + tid;
        const int sgs = ht >> 8, ksh = (ht >> 6) & 3, ln = ht & 63;
        const int row = sgs * 16 + (ln & 15);
        float4 x[2][2];
#pragma unroll
        for (int p = 0; p < 2; ++p) {
          const int ks = ksh * 2 + p, k0 = ks * 32 + (ln >> 4) * 8;
          const float* s = nh + ((size_t)(b0 + row) * N_CH + (c + 1)) * H_DIM + k0;
          x[p][0] = *(const float4*)s;
          x[p][1] = *(const float4*)(s + 4);
        }
        issueB(g + 1);
#pragma unroll
        for (int p = 0; p < 2; ++p) {
          const int ks = ksh * 2 + p;
          uint4 qv;
          qv.x = pk2(x[p][0].x, x[p][0].y); qv.y = pk2(x[p][0].z, x[p][0].w);
          qv.z = pk2(x[p][1].x, x[p][1].y); qv.w = pk2(x[p][1].z, x[p][1].w);
          *(uint4*)(smem + SM_AB + ((sgs * 8 + ks) * 64 + ln) * 16) = qv;
        }
      } else if (c < 7 && t == 7) {
        // bias(c+1): load + write in one phase (cb^1 buffer idle this channel)
        const int idx2 = tid * 2, a_s = idx2 >> 8, r_s = idx2 & 255;
        const float* bp = bB + ((size_t)(c + 1) * 4 + a_s) * R_FULL + r_s;
        float2 bv = { bp[0], bp[1] };
        issueB(g + 1);
        *(float2*)(smem + SM_BIAS(cb ^ 1) + idx2 * 4) = bv;
      } else {
        if (g + 1 < N_CH * 16) issueB(g + 1);
      }

      if (t == 0) {
        // A fragments for this wave's sample-group (reused for 16 tiles)
#pragma unroll
        for (int ks = 0; ks < 8; ++ks)
          Af[ks].q = *(const uint4*)(smem + SM_AB + ((sw * 8 + ks) * 64 + lane) * 16);
        part0[0] = part0[1] = part0[2] = part0[3] = 0.f;
        part1[0] = part1[1] = part1[2] = part1[3] = 0.f;
      }

      // ---- compute tile t for both aggregators; bias folded after MFMAs.
      const char* Bb = smem + ((t & 1) ? SM_B1 : SM_B0) + lane * 16;
      f32x4 acc0 = { 0.f, 0.f, 0.f, 0.f };
      f32x4 acc1 = { 0.f, 0.f, 0.f, 0.f };
      __builtin_amdgcn_s_setprio(1);
#pragma unroll
      for (int ks = 0; ks < 8; ++ks) {
        BF8 bf0, bf1;
        bf0.q = *(const uint4*)(Bb + (a0 * 8 + ks) * 1024);
        bf1.q = *(const uint4*)(Bb + (a1 * 8 + ks) * 1024);
        acc0 = __builtin_amdgcn_mfma_f32_16x16x32_bf16(Af[ks].v, bf0.v, acc0, 0, 0, 0);
        acc1 = __builtin_amdgcn_mfma_f32_16x16x32_bf16(Af[ks].v, bf1.v, acc1, 0, 0, 0);
      }
      __builtin_amdgcn_s_setprio(0);

      // fused scan step: part += carry[r=t] * (acc + bias)
      // (+1 at r=15 is baked into the carry write -- no extra term here)
      const float bias0 = *(const float*)(smem + SM_BIAS(cb) + (a0 * 256 + t * 16 + lr) * 4);
      const float bias1 = *(const float*)(smem + SM_BIAS(cb) + (a1 * 256 + t * 16 + lr) * 4);
      const f32x4 cv0   = *(const f32x4*)(smem + SM_C(cb) +
                            ((a0 * 4 + sw) * 16 + t) * 64 + sq16);
      const f32x4 cv1   = *(const f32x4*)(smem + SM_C(cb) +
                            ((a1 * 4 + sw) * 16 + t) * 64 + sq16);
#pragma unroll
      for (int i = 0; i < 4; ++i) {
        part0[i] += cv0[i] * (acc0[i] + bias0);
        part1[i] += cv1[i] * (acc1[i] + bias1);
      }
    }

    // ---- publish new carry into the other buffer (+1.0 baked at r==15)
    if (c < 7) {
      f32x4 p0 = part0, p1 = part1;
      if (lr == 15) {
        p0[0] += 1.f; p0[1] += 1.f; p0[2] += 1.f; p0[3] += 1.f;
        p1[0] += 1.f; p1[1] += 1.f; p1[2] += 1.f; p1[3] += 1.f;
      }
      *(f32x4*)(smem + SM_C(cb ^ 1) + ((a0 * 4 + sw) * 16 + lr) * 64 + sq16) = p0;
      *(f32x4*)(smem + SM_C(cb ^ 1) + ((a1 * 4 + sw) * 16 + lr) * 64 + sq16) = p1;
    }
  }

  // ---- epilogue: out[b][a*256+h] = carry[b][a][:] @ Uo[a][:][h] + bo[a][h]
  // One aggregator at a time (keeps only one 64-reg uo set live).
#pragma unroll 1
  for (int j = 0; j < 2; ++j) {
    const int   aj = ap * 2 + j;
    const f32x4 cr = j ? part1 : part0;
    float uo[4][16], bov[4];
#pragma unroll
    for (int chk = 0; chk < 4; ++chk) {
      bov[chk] = bo[aj * 256 + chk * 64 + lane];
#pragma unroll
      for (int r = 0; r < 16; ++r)
        uo[chk][r] = Uo[(size_t)aj * 4096 + r * 256 + chk * 64 + lane];
    }
#pragma unroll
    for (int gq = 0; gq < 4; ++gq)
#pragma unroll
      for (int i = 0; i < 4; ++i) {
        const int m = gq * 4 + i;
        float cvv[16];
#pragma unroll
        for (int r = 0; r < 16; ++r) cvv[r] = __shfl(cr[i], (gq << 4) | r, 64);
#pragma unroll
        for (int chk = 0; chk < 4; ++chk) {
          float v = bov[chk];
#pragma unroll
          for (int r = 0; r < 16; ++r) v += cvv[r] * uo[chk][r];
          out[(size_t)(rowb + m) * 1024 + aj * 256 + chk * 64 + lane] = v;
        }
      }
  }
}

extern "C" void kernel_launch(void* const* d_in, const int* in_sizes, int n_in,
                              void* d_out, int out_size, void* d_ws, size_t ws_size,
                              hipStream_t stream) {
  const float* nh = (const float*)d_in[0];   // neighbour_h (16384, 8, 256)
  const float* ty = (const float*)d_in[1];   // type_embs   (16384, 64)
  const float* U  = (const float*)d_in[2];   // U           (8, 4, 256, 272)
  const float* bB = (const float*)d_in[3];   // b           (8, 4, 1, 272)
  const float* Ut = (const float*)d_in[4];   // U_type      (4, 64, 16)
  const float* bt = (const float*)d_in[5];   // b_type      (4, 1, 16)
  const float* Uo = (const float*)d_in[6];   // U_output    (4, 16, 256)
  const float* bo = (const float*)d_in[7];   // b_output    (4, 1, 256)
  float* out = (float*)d_out;

  unsigned int* Ubf32 = (unsigned int*)d_ws; // 4 MB frag-ordered bf16 U

  prep_U_kernel<<<4096, 256, 0, stream>>>(U, Ubf32);

  tt_main<<<256, 512, 0, stream>>>(nh, ty, (const char*)d_ws,
                                   bB, Ut, bt, Uo, bo, out);
}